// Round 8
// baseline (173.842 us; speedup 1.0000x reference)
//
#include <hip/hip_runtime.h>
#include <hip/hip_fp16.h>

#define NDIM 32

// ---------- fp16-packed atomic scatter: 8 lanes per edge, 4 dims per lane ----------
// Same 16 atomic ops/edge as round 7, but half the threads / broadcast loads /
// wave count: discriminates issue-side vs L2-side atomic wall.
__global__ void k_scatter_f16x4(const int* __restrict__ rows, const int* __restrict__ cols,
                                const float* __restrict__ vals, const float4* __restrict__ feat4,
                                unsigned int* __restrict__ part, int n_edges) {
    long long gid = (long long)blockIdx.x * blockDim.x + threadIdx.x;
    int e = (int)(gid >> 3);
    if (e >= n_edges) return;
    int l = (int)(gid & 7);
    int r = rows[e];                        // broadcast across the 8-lane group
    int c = cols[e];
    float v = vals[e];
    float4 f = feat4[(long long)c * 8 + l];  // 128B/edge coalesced, 16B/lane
    unsigned short a0 = __half_as_ushort(__float2half(v * f.x));
    unsigned short a1 = __half_as_ushort(__float2half(v * f.y));
    unsigned short a2 = __half_as_ushort(__float2half(v * f.z));
    unsigned short a3 = __half_as_ushort(__float2half(v * f.w));
    unsigned int pk0 = ((unsigned int)a1 << 16) | a0;
    unsigned int pk1 = ((unsigned int)a3 << 16) | a2;
    unsigned int* dst = part + (long long)r * 16 + 2 * l;   // two adjacent half2 slots
    asm volatile("global_atomic_pk_add_f16 %0, %1, off"
                 :: "v"(dst), "v"(pk0) : "memory");
    asm volatile("global_atomic_pk_add_f16 %0, %1, off offset:4"
                 :: "v"(dst), "v"(pk1) : "memory");
}

// ---------- convert fp16 partials -> fp32 out (8 halves per thread) ----------
__global__ void k_cvt(const uint4* __restrict__ part, float4* __restrict__ out, int n16) {
    int i = blockIdx.x * blockDim.x + threadIdx.x;
    if (i >= n16) return;
    uint4 u = part[i];
    float4 a, b;
    a.x = __half2float(__ushort_as_half((unsigned short)(u.x & 0xffff)));
    a.y = __half2float(__ushort_as_half((unsigned short)(u.x >> 16)));
    a.z = __half2float(__ushort_as_half((unsigned short)(u.y & 0xffff)));
    a.w = __half2float(__ushort_as_half((unsigned short)(u.y >> 16)));
    b.x = __half2float(__ushort_as_half((unsigned short)(u.z & 0xffff)));
    b.y = __half2float(__ushort_as_half((unsigned short)(u.z >> 16)));
    b.z = __half2float(__ushort_as_half((unsigned short)(u.w & 0xffff)));
    b.w = __half2float(__ushort_as_half((unsigned short)(u.w >> 16)));
    out[2 * i + 0] = a;
    out[2 * i + 1] = b;
}

// ---------- fallback: round-1 direct fp32 atomic scatter ----------
__global__ void gc_scatter_atomic(const int* __restrict__ rows, const int* __restrict__ cols,
                                  const float* __restrict__ vals, const float* __restrict__ feat,
                                  float* __restrict__ out, int n_edges) {
    long long gid = (long long)blockIdx.x * blockDim.x + threadIdx.x;
    int e = (int)(gid >> 5);
    int d = (int)(gid & 31);
    if (e >= n_edges) return;
    float f = feat[(long long)cols[e] * NDIM + d];
    atomicAdd(&out[(long long)rows[e] * NDIM + d], vals[e] * f);
}

extern "C" void kernel_launch(void* const* d_in, const int* in_sizes, int n_in,
                              void* d_out, int out_size, void* d_ws, size_t ws_size,
                              hipStream_t stream) {
    const int*   rows = (const int*)d_in[0];
    const int*   cols = (const int*)d_in[1];
    const float* vals = (const float*)d_in[2];
    const float* feat = (const float*)d_in[3];
    float*       out  = (float*)d_out;

    const int n_edges = in_sizes[0];
    const size_t part_bytes = (size_t)out_size * sizeof(unsigned short);  // fp16 partials

    if (ws_size < part_bytes || (out_size & 7)) {
        hipMemsetAsync(out, 0, (size_t)out_size * sizeof(float), stream);
        long long total = (long long)n_edges * NDIM;
        unsigned nblock = (unsigned)((total + 255) / 256);
        gc_scatter_atomic<<<nblock, 256, 0, stream>>>(rows, cols, vals, feat, out, n_edges);
        return;
    }

    unsigned int* part = (unsigned int*)d_ws;
    hipMemsetAsync(part, 0, part_bytes, stream);   // fp16 zero == 0x0000

    long long total  = (long long)n_edges * 8;     // 8 threads per edge
    unsigned  nblock = (unsigned)((total + 255) / 256);
    k_scatter_f16x4<<<nblock, 256, 0, stream>>>(rows, cols, vals, (const float4*)feat,
                                                part, n_edges);

    int n16 = out_size / 8;                        // 8 halves per thread
    unsigned cblocks = (unsigned)((n16 + 511) / 512);
    k_cvt<<<cblocks, 512, 0, stream>>>((const uint4*)part, (float4*)out, n16);
}

// Round 9
// 98.934 us; speedup vs baseline: 1.7572x; 1.7572x over previous
//
#include <hip/hip_runtime.h>
#include <hip/hip_fp16.h>

#define NDIM 32

// ---------- fp16-packed atomic scatter: 16 lanes per edge, 2 dims per lane ----------
// Each edge's 16 lanes write one contiguous 64B row in a single wave instruction
// -> 2 x 32B sector transactions per edge (the measured minimum; atomic wall is
// ~37-40 G sector-transactions/s device-wide).
__global__ __launch_bounds__(256, 8)
void k_scatter_f16(const int* __restrict__ rows, const int* __restrict__ cols,
                   const float* __restrict__ vals, const float* __restrict__ feat,
                   unsigned int* __restrict__ part, int n_edges) {
    long long gid = (long long)blockIdx.x * blockDim.x + threadIdx.x;
    int e = (int)(gid >> 4);
    if (e >= n_edges) return;
    int l = (int)(gid & 15);
    int r = rows[e];                       // broadcast across the 16-lane group
    int c = cols[e];
    float v = vals[e];
    float2 f = ((const float2*)feat)[(long long)c * 16 + l];   // 128B/edge coalesced
    unsigned short h0 = __half_as_ushort(__float2half(v * f.x));
    unsigned short h1 = __half_as_ushort(__float2half(v * f.y));
    unsigned int pk = ((unsigned int)h1 << 16) | h0;
    unsigned int* dst = part + (long long)r * 16 + l;          // half2 slot
    asm volatile("global_atomic_pk_add_f16 %0, %1, off"
                 :: "v"(dst), "v"(pk) : "memory");
}

// ---------- convert fp16 partials -> fp32 out (8 halves per thread) ----------
__global__ __launch_bounds__(512)
void k_cvt(const uint4* __restrict__ part, float4* __restrict__ out, int n16) {
    int i = blockIdx.x * blockDim.x + threadIdx.x;
    if (i >= n16) return;
    uint4 u = part[i];
    float4 a, b;
    a.x = __half2float(__ushort_as_half((unsigned short)(u.x & 0xffff)));
    a.y = __half2float(__ushort_as_half((unsigned short)(u.x >> 16)));
    a.z = __half2float(__ushort_as_half((unsigned short)(u.y & 0xffff)));
    a.w = __half2float(__ushort_as_half((unsigned short)(u.y >> 16)));
    b.x = __half2float(__ushort_as_half((unsigned short)(u.z & 0xffff)));
    b.y = __half2float(__ushort_as_half((unsigned short)(u.z >> 16)));
    b.z = __half2float(__ushort_as_half((unsigned short)(u.w & 0xffff)));
    b.w = __half2float(__ushort_as_half((unsigned short)(u.w >> 16)));
    out[2 * i + 0] = a;
    out[2 * i + 1] = b;
}

// ---------- fallback: round-1 direct fp32 atomic scatter ----------
__global__ void gc_scatter_atomic(const int* __restrict__ rows, const int* __restrict__ cols,
                                  const float* __restrict__ vals, const float* __restrict__ feat,
                                  float* __restrict__ out, int n_edges) {
    long long gid = (long long)blockIdx.x * blockDim.x + threadIdx.x;
    int e = (int)(gid >> 5);
    int d = (int)(gid & 31);
    if (e >= n_edges) return;
    float f = feat[(long long)cols[e] * NDIM + d];
    atomicAdd(&out[(long long)rows[e] * NDIM + d], vals[e] * f);
}

extern "C" void kernel_launch(void* const* d_in, const int* in_sizes, int n_in,
                              void* d_out, int out_size, void* d_ws, size_t ws_size,
                              hipStream_t stream) {
    const int*   rows = (const int*)d_in[0];
    const int*   cols = (const int*)d_in[1];
    const float* vals = (const float*)d_in[2];
    const float* feat = (const float*)d_in[3];
    float*       out  = (float*)d_out;

    const int n_edges = in_sizes[0];
    const size_t part_bytes = (size_t)out_size * sizeof(unsigned short);  // fp16 partials

    if (ws_size < part_bytes || (out_size & 7)) {
        // fallback: pure fp32 path
        hipMemsetAsync(out, 0, (size_t)out_size * sizeof(float), stream);
        long long total = (long long)n_edges * NDIM;
        unsigned nblock = (unsigned)((total + 255) / 256);
        gc_scatter_atomic<<<nblock, 256, 0, stream>>>(rows, cols, vals, feat, out, n_edges);
        return;
    }

    unsigned int* part = (unsigned int*)d_ws;
    hipMemsetAsync(part, 0, part_bytes, stream);   // fp16 zero == 0x0000

    long long total  = (long long)n_edges * 16;    // 16 threads per edge
    unsigned  nblock = (unsigned)((total + 255) / 256);
    k_scatter_f16<<<nblock, 256, 0, stream>>>(rows, cols, vals, feat, part, n_edges);

    int n16 = out_size / 8;                        // 8 halves per thread
    unsigned cblocks = (unsigned)((n16 + 511) / 512);
    k_cvt<<<cblocks, 512, 0, stream>>>((const uint4*)part, (float4*)out, n16);
}